// Round 2
// baseline (268.900 us; speedup 1.0000x reference)
//
#include <hip/hip_runtime.h>
#include <hip/hip_bf16.h>

typedef __attribute__((ext_vector_type(8))) short bf16x8;
typedef __attribute__((ext_vector_type(4))) float f32x4;

#define T_TOK 4096
#define HDIM  1024
#define IDIM  768
#define NEXP  8
#define TOPK  2
#define NSLOT (T_TOK * TOPK)   // 8192 token-slots

#define BM  128
#define BN  64
#define BKS 64                 // K elements staged per LDS tile (2 MFMA k-steps)

__device__ __forceinline__ ushort f2bf(float f) {
  union { __hip_bfloat16 h; ushort u; } cv;
  cv.h = __float2bfloat16(f);
  return cv.u;
}

// ---- fp32 -> bf16 conversion, float4 vectorized ----
__global__ void cvt_kernel(const float* __restrict__ src, ushort* __restrict__ dst, int n4) {
  int i = blockIdx.x * blockDim.x + threadIdx.x;
  if (i >= n4) return;
  float4 v = reinterpret_cast<const float4*>(src)[i];
  ushort4 o;
  o.x = f2bf(v.x); o.y = f2bf(v.y); o.z = f2bf(v.z); o.w = f2bf(v.w);
  reinterpret_cast<ushort4*>(dst)[i] = o;
}

// ---- build per-expert (slot, weight) lists ----
__global__ void route_kernel(const int* __restrict__ sel, const float* __restrict__ rw,
                             int* __restrict__ counts, int* __restrict__ toklist,
                             float* __restrict__ wlist) {
  int slot = blockIdx.x * blockDim.x + threadIdx.x;
  if (slot >= NSLOT) return;
  int e = sel[slot];
  int idx = atomicAdd(&counts[e], 1);
  toklist[e * NSLOT + idx] = slot;
  wlist[e * NSLOT + idx] = rw[slot];
}

// ---- GEMM1: act[slot] = silu(x @ Wg^T) * (x @ Wu^T), grouped by expert ----
// A = gathered x rows [128 x 64], B = Wg/Wu rows [64 x 64] (both K-major = NT layout)
__launch_bounds__(256, 2)
__global__ void gemm_gateup(const ushort* __restrict__ xb,
                            const ushort* __restrict__ gwb,
                            const ushort* __restrict__ uwb,
                            const int* __restrict__ counts,
                            const int* __restrict__ toklist,
                            ushort* __restrict__ act) {
  const int e = blockIdx.z;
  const int cnt = counts[e];
  const int m0 = blockIdx.y * BM;
  if (m0 >= cnt) return;                 // uniform early-exit (before any barrier)
  const int n0 = blockIdx.x * BN;

  __shared__ __align__(16) ushort As[BM * BKS];    // 16 KB
  __shared__ __align__(16) ushort Bgs[BN * BKS];   // 8 KB
  __shared__ __align__(16) ushort Bus[BN * BKS];   // 8 KB
  __shared__ int slotS[BM];

  const int tid = threadIdx.x;
  if (tid < BM) {
    int entry = m0 + tid;
    slotS[tid] = (entry < cnt) ? toklist[e * NSLOT + entry] : -1;
  }
  __syncthreads();

  const int wave = tid >> 6, lane = tid & 63;
  const int wm = wave >> 1, wn = wave & 1;         // 2x2 waves -> 64x32 per wave
  const int lrow = lane & 15, lk16 = lane >> 4;

  f32x4 accg[4][2], accu[4][2];
  const f32x4 fzero = {0.f, 0.f, 0.f, 0.f};
  #pragma unroll
  for (int a = 0; a < 4; ++a)
    #pragma unroll
    for (int b = 0; b < 2; ++b) { accg[a][b] = fzero; accu[a][b] = fzero; }

  const ushort* gB = gwb + (size_t)e * IDIM * HDIM + (size_t)n0 * HDIM;
  const ushort* uB = uwb + (size_t)e * IDIM * HDIM + (size_t)n0 * HDIM;

  for (int k0 = 0; k0 < HDIM; k0 += BKS) {
    // stage A (gathered token rows); rows are 128B -> XOR-swizzle 16B chunks by row&7
    #pragma unroll
    for (int it = 0; it < 4; ++it) {
      int s = it * 256 + tid;            // 0..1023
      int r = s >> 3, c = (s & 7) << 3;  // 8 threads x 16B per 128B row
      int swz = r * BKS + ((((c >> 3) ^ r) & 7) << 3);
      int slot = slotS[r];
      bf16x8 v = {0, 0, 0, 0, 0, 0, 0, 0};
      if (slot >= 0)
        v = *reinterpret_cast<const bf16x8*>(xb + (size_t)(slot >> 1) * HDIM + k0 + c);
      *reinterpret_cast<bf16x8*>(&As[swz]) = v;
    }
    // stage Bg + Bu
    #pragma unroll
    for (int it = 0; it < 2; ++it) {
      int s = it * 256 + tid;            // 0..511
      int r = s >> 3, c = (s & 7) << 3;
      int swz = r * BKS + ((((c >> 3) ^ r) & 7) << 3);
      *reinterpret_cast<bf16x8*>(&Bgs[swz]) =
          *reinterpret_cast<const bf16x8*>(gB + (size_t)r * HDIM + k0 + c);
      *reinterpret_cast<bf16x8*>(&Bus[swz]) =
          *reinterpret_cast<const bf16x8*>(uB + (size_t)r * HDIM + k0 + c);
    }
    __syncthreads();

    #pragma unroll
    for (int ksub = 0; ksub < 2; ++ksub) {
      bf16x8 aF[4], bgF[2], buF[2];
      int chunk = ksub * 4 + lk16;
      #pragma unroll
      for (int mi = 0; mi < 4; ++mi) {
        int r = wm * 64 + mi * 16 + lrow;
        aF[mi] = *reinterpret_cast<bf16x8*>(&As[r * BKS + (((chunk ^ r) & 7) << 3)]);
      }
      #pragma unroll
      for (int ni = 0; ni < 2; ++ni) {
        int r = wn * 32 + ni * 16 + lrow;
        bgF[ni] = *reinterpret_cast<bf16x8*>(&Bgs[r * BKS + (((chunk ^ r) & 7) << 3)]);
        buF[ni] = *reinterpret_cast<bf16x8*>(&Bus[r * BKS + (((chunk ^ r) & 7) << 3)]);
      }
      #pragma unroll
      for (int mi = 0; mi < 4; ++mi)
        #pragma unroll
        for (int ni = 0; ni < 2; ++ni) {
          accg[mi][ni] = __builtin_amdgcn_mfma_f32_16x16x32_bf16(aF[mi], bgF[ni], accg[mi][ni], 0, 0, 0);
          accu[mi][ni] = __builtin_amdgcn_mfma_f32_16x16x32_bf16(aF[mi], buF[ni], accu[mi][ni], 0, 0, 0);
        }
    }
    __syncthreads();
  }

  // epilogue: y = silu(g)*u -> bf16 act[slot][i]; C/D layout: col=lane&15, row=(lane>>4)*4+j
  const int lcol = lane & 15;
  const int lrbase = (lane >> 4) * 4;
  #pragma unroll
  for (int mi = 0; mi < 4; ++mi)
    #pragma unroll
    for (int ni = 0; ni < 2; ++ni)
      #pragma unroll
      for (int j = 0; j < 4; ++j) {
        int row = wm * 64 + mi * 16 + lrbase + j;
        int slot = slotS[row];
        if (slot < 0) continue;
        int col = n0 + wn * 32 + ni * 16 + lcol;
        float g = accg[mi][ni][j];
        float u = accu[mi][ni][j];
        float y = (g / (1.0f + __expf(-g))) * u;
        act[(size_t)slot * IDIM + col] = f2bf(y);
      }
}

// ---- GEMM2: out[t] += w_slot * (act[slot] @ Wd^T), grouped by expert ----
__launch_bounds__(256, 2)
__global__ void gemm_down(const ushort* __restrict__ act,
                          const ushort* __restrict__ dwb,
                          const int* __restrict__ counts,
                          const int* __restrict__ toklist,
                          const float* __restrict__ wlist,
                          float* __restrict__ out) {
  const int e = blockIdx.z;
  const int cnt = counts[e];
  const int m0 = blockIdx.y * BM;
  if (m0 >= cnt) return;
  const int n0 = blockIdx.x * BN;

  __shared__ __align__(16) ushort As[BM * BKS];
  __shared__ __align__(16) ushort Bs[BN * BKS];
  __shared__ int slotS[BM];
  __shared__ float wS[BM];

  const int tid = threadIdx.x;
  if (tid < BM) {
    int entry = m0 + tid;
    if (entry < cnt) {
      slotS[tid] = toklist[e * NSLOT + entry];
      wS[tid] = wlist[e * NSLOT + entry];
    } else {
      slotS[tid] = -1;
      wS[tid] = 0.f;
    }
  }
  __syncthreads();

  const int wave = tid >> 6, lane = tid & 63;
  const int wm = wave >> 1, wn = wave & 1;
  const int lrow = lane & 15, lk16 = lane >> 4;

  f32x4 acc[4][2];
  const f32x4 fzero = {0.f, 0.f, 0.f, 0.f};
  #pragma unroll
  for (int a = 0; a < 4; ++a)
    #pragma unroll
    for (int b = 0; b < 2; ++b) acc[a][b] = fzero;

  const ushort* dB = dwb + (size_t)e * HDIM * IDIM + (size_t)n0 * IDIM;

  for (int k0 = 0; k0 < IDIM; k0 += BKS) {
    #pragma unroll
    for (int it = 0; it < 4; ++it) {
      int s = it * 256 + tid;
      int r = s >> 3, c = (s & 7) << 3;
      int swz = r * BKS + ((((c >> 3) ^ r) & 7) << 3);
      int slot = slotS[r];
      bf16x8 v = {0, 0, 0, 0, 0, 0, 0, 0};
      if (slot >= 0)
        v = *reinterpret_cast<const bf16x8*>(act + (size_t)slot * IDIM + k0 + c);
      *reinterpret_cast<bf16x8*>(&As[swz]) = v;
    }
    #pragma unroll
    for (int it = 0; it < 2; ++it) {
      int s = it * 256 + tid;
      int r = s >> 3, c = (s & 7) << 3;
      int swz = r * BKS + ((((c >> 3) ^ r) & 7) << 3);
      *reinterpret_cast<bf16x8*>(&Bs[swz]) =
          *reinterpret_cast<const bf16x8*>(dB + (size_t)r * IDIM + k0 + c);
    }
    __syncthreads();

    #pragma unroll
    for (int ksub = 0; ksub < 2; ++ksub) {
      bf16x8 aF[4], bF[2];
      int chunk = ksub * 4 + lk16;
      #pragma unroll
      for (int mi = 0; mi < 4; ++mi) {
        int r = wm * 64 + mi * 16 + lrow;
        aF[mi] = *reinterpret_cast<bf16x8*>(&As[r * BKS + (((chunk ^ r) & 7) << 3)]);
      }
      #pragma unroll
      for (int ni = 0; ni < 2; ++ni) {
        int r = wn * 32 + ni * 16 + lrow;
        bF[ni] = *reinterpret_cast<bf16x8*>(&Bs[r * BKS + (((chunk ^ r) & 7) << 3)]);
      }
      #pragma unroll
      for (int mi = 0; mi < 4; ++mi)
        #pragma unroll
        for (int ni = 0; ni < 2; ++ni)
          acc[mi][ni] = __builtin_amdgcn_mfma_f32_16x16x32_bf16(aF[mi], bF[ni], acc[mi][ni], 0, 0, 0);
    }
    __syncthreads();
  }

  const int lcol = lane & 15;
  const int lrbase = (lane >> 4) * 4;
  #pragma unroll
  for (int mi = 0; mi < 4; ++mi)
    #pragma unroll
    for (int ni = 0; ni < 2; ++ni)
      #pragma unroll
      for (int j = 0; j < 4; ++j) {
        int row = wm * 64 + mi * 16 + lrbase + j;
        int slot = slotS[row];
        if (slot < 0) continue;
        int t = slot >> 1;
        int col = n0 + wn * 32 + ni * 16 + lcol;
        atomicAdd(&out[(size_t)t * HDIM + col], wS[row] * acc[mi][ni][j]);
      }
}

extern "C" void kernel_launch(void* const* d_in, const int* in_sizes, int n_in,
                              void* d_out, int out_size, void* d_ws, size_t ws_size,
                              hipStream_t stream) {
  const float* hs = (const float*)d_in[0];
  const float* rw = (const float*)d_in[1];
  const int*   se = (const int*)d_in[2];
  const float* gw = (const float*)d_in[3];
  const float* uw = (const float*)d_in[4];
  const float* dw = (const float*)d_in[5];
  float* out = (float*)d_out;

  // workspace layout (bytes)
  char* base = (char*)d_ws;
  ushort* xb      = (ushort*)(base + 0);          //  8,388,608  x in bf16
  ushort* gwb     = (ushort*)(base + 8388608);    // 12,582,912  gate W bf16
  ushort* uwb     = (ushort*)(base + 20971520);   // 12,582,912  up W bf16
  ushort* dwb     = (ushort*)(base + 33554432);   // 12,582,912  down W bf16
  ushort* act     = (ushort*)(base + 46137344);   // 12,582,912  silu(g)*u bf16 [slot][I]
  int*    counts  = (int*)(base + 58720256);      //  per-expert counts
  int*    toklist = (int*)(base + 58720512);      //  262,144
  float*  wlist   = (float*)(base + 58982656);    //  262,144

  hipMemsetAsync(out, 0, (size_t)T_TOK * HDIM * sizeof(float), stream);
  hipMemsetAsync(counts, 0, 256, stream);

  int nx4 = T_TOK * HDIM / 4;
  int nw4 = NEXP * IDIM * HDIM / 4;
  cvt_kernel<<<(nx4 + 255) / 256, 256, 0, stream>>>(hs, xb, nx4);
  cvt_kernel<<<(nw4 + 255) / 256, 256, 0, stream>>>(gw, gwb, nw4);
  cvt_kernel<<<(nw4 + 255) / 256, 256, 0, stream>>>(uw, uwb, nw4);
  cvt_kernel<<<(nw4 + 255) / 256, 256, 0, stream>>>(dw, dwb, nw4);
  route_kernel<<<NSLOT / 256, 256, 0, stream>>>(se, rw, counts, toklist, wlist);
  gemm_gateup<<<dim3(IDIM / BN, NSLOT / BM, NEXP), 256, 0, stream>>>(xb, gwb, uwb, counts, toklist, act);
  gemm_down<<<dim3(HDIM / BN, NSLOT / BM, NEXP), 256, 0, stream>>>(act, dwb, counts, toklist, wlist, out);
}

// Round 3
// 253.083 us; speedup vs baseline: 1.0625x; 1.0625x over previous
//
#include <hip/hip_runtime.h>
#include <hip/hip_bf16.h>

typedef __attribute__((ext_vector_type(8))) short bf16x8;
typedef __attribute__((ext_vector_type(4))) float f32x4;

#define T_TOK 4096
#define HDIM  1024
#define IDIM  768
#define NEXP  8
#define TOPK  2
#define NSLOT (T_TOK * TOPK)   // 8192 token-slots

#define BM  128
#define BN  64
#define BKS 64                 // K elements per LDS tile (2 MFMA k-steps)

#define NX4 (T_TOK * HDIM / 4)          // 1048576 float4s of x
#define NW4 (NEXP * IDIM * HDIM / 4)    // 1572864 float4s per weight tensor

__device__ __forceinline__ ushort f2bf(float f) {
  union { __hip_bfloat16 h; ushort u; } cv;
  cv.h = __float2bfloat16(f);
  return cv.u;
}
__device__ __forceinline__ float bf2f(ushort u) {
  union { float f; uint v; } cv; cv.v = ((uint)u) << 16; return cv.f;
}

// direct global->LDS, 16B/lane; LDS dest = wave-uniform base + lane*16
__device__ __forceinline__ void gload_lds16(const ushort* g, ushort* l) {
  __builtin_amdgcn_global_load_lds(
      (const __attribute__((address_space(1))) void*)g,
      (__attribute__((address_space(3))) void*)l, 16, 0, 0);
}

// ---- fused fp32 -> bf16 conversion of x + 3 weight tensors ----
__global__ void cvt_all(const float* __restrict__ hs, const float* __restrict__ gw,
                        const float* __restrict__ uw, const float* __restrict__ dw,
                        ushort* __restrict__ xb, ushort* __restrict__ gwb,
                        ushort* __restrict__ uwb, ushort* __restrict__ dwb) {
  int i = blockIdx.x * blockDim.x + threadIdx.x;
  const float* src; ushort* dst; int off;
  if (i < NX4) { src = hs; dst = xb; off = i; }
  else {
    int j = i - NX4;
    if (j < NW4)            { src = gw; dst = gwb; off = j; }
    else if (j < 2 * NW4)   { src = uw; dst = uwb; off = j - NW4; }
    else                    { src = dw; dst = dwb; off = j - 2 * NW4; }
  }
  float4 v = reinterpret_cast<const float4*>(src)[off];
  ushort4 o;
  o.x = f2bf(v.x); o.y = f2bf(v.y); o.z = f2bf(v.z); o.w = f2bf(v.w);
  reinterpret_cast<ushort4*>(dst)[off] = o;
}

// ---- build per-expert slot lists ----
__global__ void route_kernel(const int* __restrict__ sel, int* __restrict__ counts,
                             int* __restrict__ toklist) {
  int slot = blockIdx.x * blockDim.x + threadIdx.x;
  if (slot >= NSLOT) return;
  int e = sel[slot];
  int idx = atomicAdd(&counts[e], 1);
  toklist[e * NSLOT + idx] = slot;
}

// ---- GEMM1: act[slot] = silu(x @ Wg^T) * (x @ Wu^T), grouped by expert ----
// 2-phase pipeline, global_load_lds(16B) direct staging, inverse-swizzled source.
__launch_bounds__(256, 2)
__global__ void gemm_gateup(const ushort* __restrict__ xb,
                            const ushort* __restrict__ gwb,
                            const ushort* __restrict__ uwb,
                            const int* __restrict__ counts,
                            const int* __restrict__ toklist,
                            ushort* __restrict__ act) {
  const int e = blockIdx.z;
  const int cnt = counts[e];
  const int m0 = blockIdx.y * BM;
  if (m0 >= cnt) return;
  const int n0 = blockIdx.x * BN;

  __shared__ __align__(16) ushort As[2][BM * BKS];    // 2 x 16 KB
  __shared__ __align__(16) ushort Bgs[2][BN * BKS];   // 2 x 8 KB
  __shared__ __align__(16) ushort Bus[2][BN * BKS];   // 2 x 8 KB  = 64 KB total

  const int tid = threadIdx.x;
  const int wave = tid >> 6, lane = tid & 63;
  const int wm = wave >> 1, wn = wave & 1;            // 2x2 waves, 64x32 out each
  const int lrow = lane & 15, lk16 = lane >> 4;
  const int rseg = lane >> 3;                         // row within 8-row segment
  const int ksrc = (lane & 7) ^ rseg;                 // inverse-swizzled src chunk

  // per-lane A source token rows (constant over k-loop); padding -> row 0 (masked later)
  int arow[4];
  #pragma unroll
  for (int i = 0; i < 4; ++i) {
    int entry = m0 + wave * 32 + i * 8 + rseg;
    int s = (entry < cnt) ? toklist[e * NSLOT + entry] : 0;
    arow[i] = s >> 1;                                 // token index
  }

  const ushort* gB = gwb + (size_t)e * IDIM * HDIM + (size_t)n0 * HDIM;
  const ushort* uB = uwb + (size_t)e * IDIM * HDIM + (size_t)n0 * HDIM;

  f32x4 accg[4][2], accu[4][2];
  const f32x4 fzero = {0.f, 0.f, 0.f, 0.f};
  #pragma unroll
  for (int a = 0; a < 4; ++a)
    #pragma unroll
    for (int b = 0; b < 2; ++b) { accg[a][b] = fzero; accu[a][b] = fzero; }

  auto stage = [&](int buf, int k0) {
    #pragma unroll
    for (int i = 0; i < 4; ++i) {
      int seg = wave * 4 + i;                         // 8 rows x 128B per seg
      gload_lds16(xb + (size_t)arow[i] * HDIM + k0 + ksrc * 8, &As[buf][seg * 512]);
    }
    #pragma unroll
    for (int i = 0; i < 2; ++i) {
      int seg = wave * 2 + i;
      int br = seg * 8 + rseg;
      gload_lds16(gB + (size_t)br * HDIM + k0 + ksrc * 8, &Bgs[buf][seg * 512]);
      gload_lds16(uB + (size_t)br * HDIM + k0 + ksrc * 8, &Bus[buf][seg * 512]);
    }
  };

  auto compute = [&](int buf) {
    #pragma unroll
    for (int ksub = 0; ksub < 2; ++ksub) {
      bf16x8 aF[4], bgF[2], buF[2];
      const int chunk = ksub * 4 + lk16;
      #pragma unroll
      for (int mi = 0; mi < 4; ++mi) {
        int r = wm * 64 + mi * 16 + lrow;
        aF[mi] = *reinterpret_cast<const bf16x8*>(&As[buf][r * 64 + ((chunk ^ (r & 7)) & 7) * 8]);
      }
      #pragma unroll
      for (int ni = 0; ni < 2; ++ni) {
        int r = wn * 32 + ni * 16 + lrow;
        bgF[ni] = *reinterpret_cast<const bf16x8*>(&Bgs[buf][r * 64 + ((chunk ^ (r & 7)) & 7) * 8]);
        buF[ni] = *reinterpret_cast<const bf16x8*>(&Bus[buf][r * 64 + ((chunk ^ (r & 7)) & 7) * 8]);
      }
      #pragma unroll
      for (int mi = 0; mi < 4; ++mi)
        #pragma unroll
        for (int ni = 0; ni < 2; ++ni) {
          accg[mi][ni] = __builtin_amdgcn_mfma_f32_16x16x32_bf16(aF[mi], bgF[ni], accg[mi][ni], 0, 0, 0);
          accu[mi][ni] = __builtin_amdgcn_mfma_f32_16x16x32_bf16(aF[mi], buF[ni], accu[mi][ni], 0, 0, 0);
        }
    }
  };

  stage(0, 0);
  __syncthreads();
  #pragma unroll 1
  for (int t = 0; t < HDIM / BKS; t += 2) {
    if (t + 1 < HDIM / BKS) stage(1, (t + 1) * BKS);
    compute(0);
    __syncthreads();                                  // drains vmcnt -> buf1 ready
    if (t + 2 < HDIM / BKS) stage(0, (t + 2) * BKS);
    compute(1);
    __syncthreads();
  }

  // epilogue: y = silu(g)*u -> bf16 act[slot][col]; C/D: col=lane&15, row=(lane>>4)*4+j
  const int lcol = lane & 15;
  const int lrb = (lane >> 4) * 4;
  #pragma unroll
  for (int mi = 0; mi < 4; ++mi)
    #pragma unroll
    for (int j = 0; j < 4; ++j) {
      int row = wm * 64 + mi * 16 + lrb + j;
      int entry = m0 + row;
      if (entry >= cnt) continue;
      int slot = toklist[e * NSLOT + entry];
      #pragma unroll
      for (int ni = 0; ni < 2; ++ni) {
        int col = n0 + wn * 32 + ni * 16 + lcol;
        float g = accg[mi][ni][j];
        float u = accu[mi][ni][j];
        float y = (g / (1.0f + __expf(-g))) * u;
        act[(size_t)slot * IDIM + col] = f2bf(y);
      }
    }
}

// ---- GEMM2: yact[slot] = act[slot] @ Wd^T (unweighted, no atomics) ----
__launch_bounds__(256, 3)
__global__ void gemm_down(const ushort* __restrict__ act,
                          const ushort* __restrict__ dwb,
                          const int* __restrict__ counts,
                          const int* __restrict__ toklist,
                          ushort* __restrict__ yact) {
  const int e = blockIdx.z;
  const int cnt = counts[e];
  const int m0 = blockIdx.y * BM;
  if (m0 >= cnt) return;
  const int n0 = blockIdx.x * BN;

  __shared__ __align__(16) ushort As[2][BM * BKS];    // 32 KB
  __shared__ __align__(16) ushort Bs[2][BN * BKS];    // 16 KB  = 48 KB total

  const int tid = threadIdx.x;
  const int wave = tid >> 6, lane = tid & 63;
  const int wm = wave >> 1, wn = wave & 1;
  const int lrow = lane & 15, lk16 = lane >> 4;
  const int rseg = lane >> 3;
  const int ksrc = (lane & 7) ^ rseg;

  int arow[4];                                        // act rows = slot ids
  #pragma unroll
  for (int i = 0; i < 4; ++i) {
    int entry = m0 + wave * 32 + i * 8 + rseg;
    arow[i] = (entry < cnt) ? toklist[e * NSLOT + entry] : 0;
  }

  const ushort* dB = dwb + (size_t)e * HDIM * IDIM + (size_t)n0 * IDIM;

  f32x4 acc[4][2];
  const f32x4 fzero = {0.f, 0.f, 0.f, 0.f};
  #pragma unroll
  for (int a = 0; a < 4; ++a)
    #pragma unroll
    for (int b = 0; b < 2; ++b) acc[a][b] = fzero;

  auto stage = [&](int buf, int k0) {
    #pragma unroll
    for (int i = 0; i < 4; ++i) {
      int seg = wave * 4 + i;
      gload_lds16(act + (size_t)arow[i] * IDIM + k0 + ksrc * 8, &As[buf][seg * 512]);
    }
    #pragma unroll
    for (int i = 0; i < 2; ++i) {
      int seg = wave * 2 + i;
      int br = seg * 8 + rseg;
      gload_lds16(dB + (size_t)br * IDIM + k0 + ksrc * 8, &Bs[buf][seg * 512]);
    }
  };

  auto compute = [&](int buf) {
    #pragma unroll
    for (int ksub = 0; ksub < 2; ++ksub) {
      bf16x8 aF[4], bF[2];
      const int chunk = ksub * 4 + lk16;
      #pragma unroll
      for (int mi = 0; mi < 4; ++mi) {
        int r = wm * 64 + mi * 16 + lrow;
        aF[mi] = *reinterpret_cast<const bf16x8*>(&As[buf][r * 64 + ((chunk ^ (r & 7)) & 7) * 8]);
      }
      #pragma unroll
      for (int ni = 0; ni < 2; ++ni) {
        int r = wn * 32 + ni * 16 + lrow;
        bF[ni] = *reinterpret_cast<const bf16x8*>(&Bs[buf][r * 64 + ((chunk ^ (r & 7)) & 7) * 8]);
      }
      #pragma unroll
      for (int mi = 0; mi < 4; ++mi)
        #pragma unroll
        for (int ni = 0; ni < 2; ++ni)
          acc[mi][ni] = __builtin_amdgcn_mfma_f32_16x16x32_bf16(aF[mi], bF[ni], acc[mi][ni], 0, 0, 0);
    }
  };

  stage(0, 0);
  __syncthreads();
  #pragma unroll 1
  for (int t = 0; t < IDIM / BKS; t += 2) {
    if (t + 1 < IDIM / BKS) stage(1, (t + 1) * BKS);
    compute(0);
    __syncthreads();
    if (t + 2 < IDIM / BKS) stage(0, (t + 2) * BKS);
    compute(1);
    __syncthreads();
  }

  const int lcol = lane & 15;
  const int lrb = (lane >> 4) * 4;
  #pragma unroll
  for (int mi = 0; mi < 4; ++mi)
    #pragma unroll
    for (int j = 0; j < 4; ++j) {
      int row = wm * 64 + mi * 16 + lrb + j;
      int entry = m0 + row;
      if (entry >= cnt) continue;
      int slot = toklist[e * NSLOT + entry];
      #pragma unroll
      for (int ni = 0; ni < 2; ++ni) {
        int col = n0 + wn * 32 + ni * 16 + lcol;
        yact[(size_t)slot * HDIM + col] = f2bf(acc[mi][ni][j]);
      }
    }
}

// ---- combine: out[t] = rw[2t]*yact[2t] + rw[2t+1]*yact[2t+1] ----
__global__ void combine_kernel(const ushort* __restrict__ yact, const float* __restrict__ rw,
                               float* __restrict__ out) {
  int i = blockIdx.x * blockDim.x + threadIdx.x;      // T_TOK*HDIM/8 threads
  int t = i >> 7;                                     // 128 threads per token row
  int h0 = (i & 127) << 3;
  const bf16x8 y0 = *reinterpret_cast<const bf16x8*>(yact + (size_t)(2 * t) * HDIM + h0);
  const bf16x8 y1 = *reinterpret_cast<const bf16x8*>(yact + (size_t)(2 * t + 1) * HDIM + h0);
  float w0 = rw[2 * t], w1 = rw[2 * t + 1];
  float o[8];
  #pragma unroll
  for (int j = 0; j < 8; ++j)
    o[j] = w0 * bf2f((ushort)y0[j]) + w1 * bf2f((ushort)y1[j]);
  float4* op = reinterpret_cast<float4*>(out + (size_t)t * HDIM + h0);
  op[0] = make_float4(o[0], o[1], o[2], o[3]);
  op[1] = make_float4(o[4], o[5], o[6], o[7]);
}

extern "C" void kernel_launch(void* const* d_in, const int* in_sizes, int n_in,
                              void* d_out, int out_size, void* d_ws, size_t ws_size,
                              hipStream_t stream) {
  const float* hs = (const float*)d_in[0];
  const float* rw = (const float*)d_in[1];
  const int*   se = (const int*)d_in[2];
  const float* gw = (const float*)d_in[3];
  const float* uw = (const float*)d_in[4];
  const float* dw = (const float*)d_in[5];
  float* out = (float*)d_out;

  // workspace layout (bytes); yact aliases gwb+uwb (dead after gemm_gateup)
  char* base = (char*)d_ws;
  ushort* xb      = (ushort*)(base + 0);           //  8,388,608
  ushort* gwb     = (ushort*)(base + 8388608);     // 12,582,912
  ushort* uwb     = (ushort*)(base + 20971520);    // 12,582,912
  ushort* dwb     = (ushort*)(base + 33554432);    // 12,582,912
  ushort* act     = (ushort*)(base + 46137344);    // 12,582,912  [slot][IDIM] bf16
  ushort* yact    = (ushort*)(base + 8388608);     // 16,777,216  [slot][HDIM] bf16 (aliases gwb/uwb)
  int*    toklist = (int*)(base + 58720256);       //    262,144
  int*    counts  = (int*)(base + 58982400);       //         32

  hipMemsetAsync(counts, 0, 256, stream);

  int total4 = NX4 + 3 * NW4;
  cvt_all<<<(total4 + 255) / 256, 256, 0, stream>>>(hs, gw, uw, dw, xb, gwb, uwb, dwb);
  route_kernel<<<NSLOT / 256, 256, 0, stream>>>(se, counts, toklist);
  gemm_gateup<<<dim3(IDIM / BN, NSLOT / BM, NEXP), 256, 0, stream>>>(xb, gwb, uwb, counts, toklist, act);
  gemm_down<<<dim3(HDIM / BN, NSLOT / BM, NEXP), 256, 0, stream>>>(act, dwb, counts, toklist, yact);
  combine_kernel<<<T_TOK * HDIM / 8 / 256, 256, 0, stream>>>(yact, rw, out);
}

// Round 5
// 237.203 us; speedup vs baseline: 1.1336x; 1.0669x over previous
//
#include <hip/hip_runtime.h>
#include <hip/hip_bf16.h>

typedef __attribute__((ext_vector_type(8))) short bf16x8;
typedef __attribute__((ext_vector_type(4))) float f32x4;

#define T_TOK 4096
#define HDIM  1024
#define IDIM  768
#define NEXP  8
#define TOPK  2
#define NSLOT (T_TOK * TOPK)   // 8192 token-slots

#define BM  128
#define BN  64
#define BKS 32                 // K elements per LDS tile (1 MFMA k-step) — m97 config

#define NX4 (T_TOK * HDIM / 4)
#define NW4 (NEXP * IDIM * HDIM / 4)

__device__ __forceinline__ ushort f2bf(float f) {
  union { __hip_bfloat16 h; ushort u; } cv;
  cv.h = __float2bfloat16(f);
  return cv.u;
}
__device__ __forceinline__ float bf2f(ushort u) {
  union { float f; uint v; } cv; cv.v = ((uint)u) << 16; return cv.f;
}

__device__ __forceinline__ void gload_lds16(const ushort* g, ushort* l) {
  __builtin_amdgcn_global_load_lds(
      (const __attribute__((address_space(1))) void*)g,
      (__attribute__((address_space(3))) void*)l, 16, 0, 0);
}

// ---- fused fp32 -> bf16 conversion of x + 3 weight tensors ----
__global__ void cvt_all(const float* __restrict__ hs, const float* __restrict__ gw,
                        const float* __restrict__ uw, const float* __restrict__ dw,
                        ushort* __restrict__ xb, ushort* __restrict__ gwb,
                        ushort* __restrict__ uwb, ushort* __restrict__ dwb) {
  int i = blockIdx.x * blockDim.x + threadIdx.x;
  const float* src; ushort* dst; int off;
  if (i < NX4) { src = hs; dst = xb; off = i; }
  else {
    int j = i - NX4;
    if (j < NW4)            { src = gw; dst = gwb; off = j; }
    else if (j < 2 * NW4)   { src = uw; dst = uwb; off = j - NW4; }
    else                    { src = dw; dst = dwb; off = j - 2 * NW4; }
  }
  float4 v = reinterpret_cast<const float4*>(src)[off];
  ushort4 o;
  o.x = f2bf(v.x); o.y = f2bf(v.y); o.z = f2bf(v.z); o.w = f2bf(v.w);
  reinterpret_cast<ushort4*>(dst)[off] = o;
}

// ---- build per-expert slot lists ----
__global__ void route_kernel(const int* __restrict__ sel, int* __restrict__ counts,
                             int* __restrict__ toklist) {
  int slot = blockIdx.x * blockDim.x + threadIdx.x;
  if (slot >= NSLOT) return;
  int e = sel[slot];
  int idx = atomicAdd(&counts[e], 1);
  toklist[e * NSLOT + idx] = slot;
}

// swizzle helpers for 64B rows (4 x 16B chunks):
//   read  (row r, chunk c) at stored chunk c ^ ((r>>1)&3)
//   stage lane l (row_in_seg = l>>2, slot chunk = l&3) fetches global chunk (l&3)^((l>>3)&3)

// ---- GEMM1: act[slot] = silu(x @ Wg^T) * (x @ Wu^T), grouped by expert ----
__launch_bounds__(256, 3)
__global__ void gemm_gateup(const ushort* __restrict__ xb,
                            const ushort* __restrict__ gwb,
                            const ushort* __restrict__ uwb,
                            const int* __restrict__ counts,
                            const int* __restrict__ toklist,
                            ushort* __restrict__ act) {
  const int b = blockIdx.x;
  const int e = b & 7;                    // expert == XCD (L2 locality for weights + x)
  const int r = b >> 3;
  const int nt = r % 12, mt = r / 12;     // mt slowest -> active blocks front-loaded
  const int cnt = counts[e];
  const int m0 = mt * BM;
  if (m0 >= cnt) return;
  const int n0 = nt * BN;

  __shared__ __align__(16) ushort As[2][BM * BKS];    // 2 x 8 KB
  __shared__ __align__(16) ushort Bgs[2][BN * BKS];   // 2 x 4 KB
  __shared__ __align__(16) ushort Bus[2][BN * BKS];   // 2 x 4 KB  = 32 KB

  const int tid = threadIdx.x;
  const int wave = tid >> 6, lane = tid & 63;
  const int wm = wave >> 1, wn = wave & 1;            // 2x2 waves, 64x32 out each
  const int lrow = lane & 15, lk16 = lane >> 4;
  const int rl = lane >> 2;                           // row within 16-row segment
  const int gck = ((lane & 3) ^ ((lane >> 3) & 3)) << 3;  // src chunk elem offset

  // A: wave stages segs {wave, wave+4} (16 rows each); B: seg {wave}
  const int ent0 = m0 + wave * 16 + rl;
  const int ent1 = ent0 + 64;
  const int arow0 = (ent0 < cnt) ? (toklist[e * NSLOT + ent0] >> 1) : 0;
  const int arow1 = (ent1 < cnt) ? (toklist[e * NSLOT + ent1] >> 1) : 0;
  const int brow = wave * 16 + rl;                    // 0..63

  const ushort* aP0 = xb + (size_t)arow0 * HDIM + gck;
  const ushort* aP1 = xb + (size_t)arow1 * HDIM + gck;
  const ushort* gP = gwb + (size_t)e * IDIM * HDIM + (size_t)(n0 + brow) * HDIM + gck;
  const ushort* uP = uwb + (size_t)e * IDIM * HDIM + (size_t)(n0 + brow) * HDIM + gck;

  f32x4 accg[4][2], accu[4][2];
  const f32x4 fzero = {0.f, 0.f, 0.f, 0.f};
  #pragma unroll
  for (int a = 0; a < 4; ++a)
    #pragma unroll
    for (int c = 0; c < 2; ++c) { accg[a][c] = fzero; accu[a][c] = fzero; }

  auto stage = [&](int buf, int k0) {
    gload_lds16(aP0 + k0, &As[buf][wave * 512]);
    gload_lds16(aP1 + k0, &As[buf][(wave + 4) * 512]);
    gload_lds16(gP + k0, &Bgs[buf][wave * 512]);
    gload_lds16(uP + k0, &Bus[buf][wave * 512]);
  };

  const int swzc = ((lk16 ^ ((lrow >> 1) & 3)) << 3);
  auto compute = [&](int buf) {
    bf16x8 aF[4], bgF[2], buF[2];
    #pragma unroll
    for (int mi = 0; mi < 4; ++mi) {
      int rr = wm * 64 + mi * 16 + lrow;
      aF[mi] = *reinterpret_cast<const bf16x8*>(&As[buf][rr * 32 + swzc]);
    }
    #pragma unroll
    for (int ni = 0; ni < 2; ++ni) {
      int rr = wn * 32 + ni * 16 + lrow;
      bgF[ni] = *reinterpret_cast<const bf16x8*>(&Bgs[buf][rr * 32 + swzc]);
      buF[ni] = *reinterpret_cast<const bf16x8*>(&Bus[buf][rr * 32 + swzc]);
    }
    #pragma unroll
    for (int mi = 0; mi < 4; ++mi)
      #pragma unroll
      for (int ni = 0; ni < 2; ++ni) {
        accg[mi][ni] = __builtin_amdgcn_mfma_f32_16x16x32_bf16(aF[mi], bgF[ni], accg[mi][ni], 0, 0, 0);
        accu[mi][ni] = __builtin_amdgcn_mfma_f32_16x16x32_bf16(aF[mi], buF[ni], accu[mi][ni], 0, 0, 0);
      }
  };

  stage(0, 0);
  __syncthreads();
  #pragma unroll 1
  for (int t = 0; t < HDIM / BKS; t += 2) {
    if (t + 1 < HDIM / BKS) stage(1, (t + 1) * BKS);
    compute(0);
    __syncthreads();
    if (t + 2 < HDIM / BKS) stage(0, (t + 2) * BKS);
    compute(1);
    __syncthreads();
  }

  // epilogue: y = silu(g)*u -> bf16 act[slot][col]; C/D: col=lane&15, row=(lane>>4)*4+j
  const int lcol = lane & 15;
  const int lrb = (lane >> 4) * 4;
  #pragma unroll
  for (int mi = 0; mi < 4; ++mi)
    #pragma unroll
    for (int j = 0; j < 4; ++j) {
      int row = wm * 64 + mi * 16 + lrb + j;
      int entry = m0 + row;
      if (entry >= cnt) continue;
      int slot = toklist[e * NSLOT + entry];
      #pragma unroll
      for (int ni = 0; ni < 2; ++ni) {
        int col = n0 + wn * 32 + ni * 16 + lcol;
        float g = accg[mi][ni][j];
        float u = accu[mi][ni][j];
        float y = (g / (1.0f + __expf(-g))) * u;
        act[(size_t)slot * IDIM + col] = f2bf(y);
      }
    }
}

// ---- GEMM2: yact[slot] = act[slot] @ Wd^T (unweighted, no atomics) ----
__launch_bounds__(256, 4)
__global__ void gemm_down(const ushort* __restrict__ act,
                          const ushort* __restrict__ dwb,
                          const int* __restrict__ counts,
                          const int* __restrict__ toklist,
                          ushort* __restrict__ yact) {
  const int b = blockIdx.x;
  const int e = b & 7;
  const int r = b >> 3;
  const int nt = r & 15, mt = r >> 4;
  const int cnt = counts[e];
  const int m0 = mt * BM;
  if (m0 >= cnt) return;
  const int n0 = nt * BN;

  __shared__ __align__(16) ushort As[2][BM * BKS];    // 2 x 8 KB
  __shared__ __align__(16) ushort Bs[2][BN * BKS];    // 2 x 4 KB  = 24 KB

  const int tid = threadIdx.x;
  const int wave = tid >> 6, lane = tid & 63;
  const int wm = wave >> 1, wn = wave & 1;
  const int lrow = lane & 15, lk16 = lane >> 4;
  const int rl = lane >> 2;
  const int gck = ((lane & 3) ^ ((lane >> 3) & 3)) << 3;

  const int ent0 = m0 + wave * 16 + rl;
  const int ent1 = ent0 + 64;
  const int arow0 = (ent0 < cnt) ? toklist[e * NSLOT + ent0] : 0;  // slot id
  const int arow1 = (ent1 < cnt) ? toklist[e * NSLOT + ent1] : 0;
  const int brow = wave * 16 + rl;

  const ushort* aP0 = act + (size_t)arow0 * IDIM + gck;
  const ushort* aP1 = act + (size_t)arow1 * IDIM + gck;
  const ushort* dP = dwb + (size_t)e * HDIM * IDIM + (size_t)(n0 + brow) * IDIM + gck;

  f32x4 acc[4][2];
  const f32x4 fzero = {0.f, 0.f, 0.f, 0.f};
  #pragma unroll
  for (int a = 0; a < 4; ++a)
    #pragma unroll
    for (int c = 0; c < 2; ++c) acc[a][c] = fzero;

  auto stage = [&](int buf, int k0) {
    gload_lds16(aP0 + k0, &As[buf][wave * 512]);
    gload_lds16(aP1 + k0, &As[buf][(wave + 4) * 512]);
    gload_lds16(dP + k0, &Bs[buf][wave * 512]);
  };

  const int swzc = ((lk16 ^ ((lrow >> 1) & 3)) << 3);
  auto compute = [&](int buf) {
    bf16x8 aF[4], bF[2];
    #pragma unroll
    for (int mi = 0; mi < 4; ++mi) {
      int rr = wm * 64 + mi * 16 + lrow;
      aF[mi] = *reinterpret_cast<const bf16x8*>(&As[buf][rr * 32 + swzc]);
    }
    #pragma unroll
    for (int ni = 0; ni < 2; ++ni) {
      int rr = wn * 32 + ni * 16 + lrow;
      bF[ni] = *reinterpret_cast<const bf16x8*>(&Bs[buf][rr * 32 + swzc]);
    }
    #pragma unroll
    for (int mi = 0; mi < 4; ++mi)
      #pragma unroll
      for (int ni = 0; ni < 2; ++ni)
        acc[mi][ni] = __builtin_amdgcn_mfma_f32_16x16x32_bf16(aF[mi], bF[ni], acc[mi][ni], 0, 0, 0);
  };

  stage(0, 0);
  __syncthreads();
  #pragma unroll 1
  for (int t = 0; t < IDIM / BKS; t += 2) {
    if (t + 1 < IDIM / BKS) stage(1, (t + 1) * BKS);
    compute(0);
    __syncthreads();
    if (t + 2 < IDIM / BKS) stage(0, (t + 2) * BKS);
    compute(1);
    __syncthreads();
  }

  const int lcol = lane & 15;
  const int lrb = (lane >> 4) * 4;
  #pragma unroll
  for (int mi = 0; mi < 4; ++mi)
    #pragma unroll
    for (int j = 0; j < 4; ++j) {
      int row = wm * 64 + mi * 16 + lrb + j;
      int entry = m0 + row;
      if (entry >= cnt) continue;
      int slot = toklist[e * NSLOT + entry];
      #pragma unroll
      for (int ni = 0; ni < 2; ++ni) {
        int col = n0 + wn * 32 + ni * 16 + lcol;
        yact[(size_t)slot * HDIM + col] = f2bf(acc[mi][ni][j]);
      }
    }
}

// ---- combine: out[t] = rw[2t]*yact[2t] + rw[2t+1]*yact[2t+1] ----
__global__ void combine_kernel(const ushort* __restrict__ yact, const float* __restrict__ rw,
                               float* __restrict__ out) {
  int i = blockIdx.x * blockDim.x + threadIdx.x;
  int t = i >> 7;
  int h0 = (i & 127) << 3;
  const bf16x8 y0 = *reinterpret_cast<const bf16x8*>(yact + (size_t)(2 * t) * HDIM + h0);
  const bf16x8 y1 = *reinterpret_cast<const bf16x8*>(yact + (size_t)(2 * t + 1) * HDIM + h0);
  float w0 = rw[2 * t], w1 = rw[2 * t + 1];
  float o[8];
  #pragma unroll
  for (int j = 0; j < 8; ++j)
    o[j] = w0 * bf2f((ushort)y0[j]) + w1 * bf2f((ushort)y1[j]);
  float4* op = reinterpret_cast<float4*>(out + (size_t)t * HDIM + h0);
  op[0] = make_float4(o[0], o[1], o[2], o[3]);
  op[1] = make_float4(o[4], o[5], o[6], o[7]);
}

extern "C" void kernel_launch(void* const* d_in, const int* in_sizes, int n_in,
                              void* d_out, int out_size, void* d_ws, size_t ws_size,
                              hipStream_t stream) {
  const float* hs = (const float*)d_in[0];
  const float* rw = (const float*)d_in[1];
  const int*   se = (const int*)d_in[2];
  const float* gw = (const float*)d_in[3];
  const float* uw = (const float*)d_in[4];
  const float* dw = (const float*)d_in[5];
  float* out = (float*)d_out;

  // workspace layout (bytes); yact aliases gwb+uwb (dead after gemm_gateup)
  char* base = (char*)d_ws;
  ushort* xb      = (ushort*)(base + 0);           //  8,388,608
  ushort* gwb     = (ushort*)(base + 8388608);     // 12,582,912
  ushort* uwb     = (ushort*)(base + 20971520);    // 12,582,912
  ushort* dwb     = (ushort*)(base + 33554432);    // 12,582,912
  ushort* act     = (ushort*)(base + 46137344);    // 12,582,912  [slot][IDIM] bf16
  ushort* yact    = (ushort*)(base + 8388608);     // 16,777,216  [slot][HDIM] bf16 (aliases gwb/uwb)
  int*    toklist = (int*)(base + 58720256);       //    262,144
  int*    counts  = (int*)(base + 58982400);       //         32

  hipMemsetAsync(counts, 0, 256, stream);

  int total4 = NX4 + 3 * NW4;
  cvt_all<<<(total4 + 255) / 256, 256, 0, stream>>>(hs, gw, uw, dw, xb, gwb, uwb, dwb);
  route_kernel<<<NSLOT / 256, 256, 0, stream>>>(se, counts, toklist);
  gemm_gateup<<<8 * 12 * (NSLOT / BM), 256, 0, stream>>>(xb, gwb, uwb, counts, toklist, act);
  gemm_down<<<8 * 16 * (NSLOT / BM), 256, 0, stream>>>(act, dwb, counts, toklist, yact);
  combine_kernel<<<T_TOK * HDIM / 8 / 256, 256, 0, stream>>>(yact, rw, out);
}